// Round 6
// baseline (167.022 us; speedup 1.0000x reference)
//
#include <hip/hip_runtime.h>
#include <hip/hip_bf16.h>
#include <stdint.h>

#define SDEP 128
#define NRES 256
#define CZQ 128
#define NT 8   // tiles per block (outer kernel)

typedef __bf16 v8bf __attribute__((ext_vector_type(8)));
typedef __bf16 v4bf __attribute__((ext_vector_type(4)));
typedef float v16f __attribute__((ext_vector_type(16)));

// full-wave sum via DPP (VALU pipe, no LDS). Result valid in lane 63.
__device__ __forceinline__ float dpp_wave_sum(float x) {
  float t;
#define STEP(ctrl)                                                         \
  t = __builtin_bit_cast(float, __builtin_amdgcn_update_dpp(               \
          0, __builtin_bit_cast(int, x), ctrl, 0xF, 0xF, true));           \
  x += t;
  STEP(0x111)
  STEP(0x112)
  STEP(0x114)
  STEP(0x118)
  STEP(0x142)
  STEP(0x143)
#undef STEP
  return x;
}
__device__ __forceinline__ float lane63(float x) {
  return __builtin_bit_cast(float,
      __builtin_amdgcn_readlane(__builtin_bit_cast(int, x), 63));
}

#define MFMA32(a, b, c) __builtin_amdgcn_mfma_f32_32x32x16_bf16(a, b, c, 0, 0, 0)

// ---------------- Kernel A: fused prep + LN + projections ------------
// 256 blocks x 512 thr, 1 block/CU, 1 round. (unchanged, proven)
__global__ __launch_bounds__(512, 2) void fusedA_kernel(
    const float* __restrict__ msa, const float* __restrict__ lnw,
    const float* __restrict__ lnb, const float* __restrict__ wl,
    const float* __restrict__ wr, const float* __restrict__ mask,
    const float* __restrict__ wo, const float* __restrict__ bl,
    const float* __restrict__ br,
    __bf16* __restrict__ At2, __bf16* __restrict__ Bt2,
    float* __restrict__ rnorm, __bf16* __restrict__ wot4)
{
  __shared__ __bf16 xs[128 * 258];      // 66 KB
  __shared__ __bf16 wcs[16384];         // 32 KB
  __shared__ __bf16 Ls[8 * 32 * 36];    // 18 KB

  const int i = blockIdx.x, t = threadIdx.x;
  const int w = t >> 6, lane = t & 63;
  const int half = lane >> 5, l31 = lane & 31;
  const int sb = w >> 1, nh = w & 1;

  #pragma unroll
  for (int u = 0; u < 32; ++u) {
    int idx = u * 512 + t;
    int j = idx & 7, n = (idx >> 3) & 31, hf = (idx >> 8) & 1;
    int ks = (idx >> 9) & 15, tile = idx >> 13;
    const float* wsrc = tile ? wr : wl;
    wcs[idx] = (__bf16)wsrc[(ks * 16 + hf * 8 + j) * 32 + n];
  }

  const float4 wv4 = ((const float4*)lnw)[lane];
  const float4 bv4 = ((const float4*)lnb)[lane];

  #pragma unroll 8
  for (int r = 0; r < 16; ++r) {
    const int s = sb * 32 + nh * 16 + r;
    float4 x = ((const float4*)(msa + ((size_t)s * 256 + i) * 256))[lane];
    float s1 = dpp_wave_sum(x.x + x.y + x.z + x.w);
    float s2 = dpp_wave_sum(x.x * x.x + x.y * x.y + x.z * x.z + x.w * x.w);
    float mu = lane63(s1) * (1.f / 256.f);
    float var = lane63(s2) * (1.f / 256.f) - mu * mu;
    float rs = rsqrtf(var + 1e-5f);
    v4bf o;
    o[0] = (__bf16)((x.x - mu) * rs * wv4.x + bv4.x);
    o[1] = (__bf16)((x.y - mu) * rs * wv4.y + bv4.y);
    o[2] = (__bf16)((x.z - mu) * rs * wv4.z + bv4.z);
    o[3] = (__bf16)((x.w - mu) * rs * wv4.w + bv4.w);
    *(v4bf*)(xs + s * 258 + lane * 4) = o;
  }
  __syncthreads();

  v16f acc;
  #pragma unroll
  for (int r = 0; r < 16; ++r) acc[r] = 0.f;

  const __bf16* xrow = xs + (sb * 32 + l31) * 258 + half * 8;
  const __bf16* bbase = wcs + nh * 8192 + half * 256 + l31 * 8;
  #pragma unroll
  for (int ks = 0; ks < 16; ++ks) {
    v8bf a = *(const v8bf*)(xrow + ks * 16);
    v8bf b = *(const v8bf*)(bbase + ks * 512);
    acc = MFMA32(a, b, acc);
  }

  __bf16* Lw = Ls + w * 32 * 36;
  const float bias = (nh ? br : bl)[l31];
  #pragma unroll
  for (int r = 0; r < 16; ++r) {
    int sl = (r & 3) + 8 * (r >> 2) + 4 * half;
    float mv = mask[(sb * 32 + sl) * NRES + i];
    Lw[l31 * 36 + sl] = (__bf16)((acc[r] + bias) * mv);
  }

  __bf16* dst = nh ? Bt2 : At2;
  const int c = lane >> 1, jq = (lane & 1) * 4;
  #pragma unroll
  for (int o = 0; o < 4; ++o) {
    v4bf v = *(const v4bf*)(Lw + c * 36 + o * 8 + jq);
    *(v4bf*)(dst + ((size_t)i * 16 + sb * 4 + o) * 256 + lane * 4) = v;
  }

  if (i < 128) {
    const int b = i * 2 + (t >> 8), col = t & 255;
    float a0 = 0.f;
    #pragma unroll 4
    for (int s = 0; s < SDEP; ++s)
      a0 += mask[s * NRES + b] * mask[s * NRES + col];
    rnorm[b * NRES + col] = 1.f / fmaxf(a0, 1.f);
  } else {
    #pragma unroll
    for (int u = 0; u < 2; ++u) {
      int idx = (i - 128) * 1024 + u * 512 + t;
      int j = idx & 7, lc = (idx >> 3) & 63, kk = (idx >> 9) & 63, zg = idx >> 15;
      int k = kk * 16 + (lc >> 5) * 8 + j;
      int z = zg * 32 + (lc & 31);
      wot4[idx] = (__bf16)wo[k * CZQ + z];
    }
  }
}

// ---------------- Kernel B: wave-specialized outer + out proj --------
// R12: producer/consumer wave specialization (m114: different-mix waves
// co-schedule on a SIMD; per-SIMD pairing wave w & w+4 => 1 G1 + 1 G2).
//  - waves 0-3 (G1): load A/B from L2, MFMA outer product, write Ps.
//  - waves 4-7 (G2): stream wot, ds_read Ps rows, MFMA, store out.
//  - Ps double-buffered, ONE barrier per tile-step, no redb (full-K G2).
//  - 256 blocks x 8 tiles (9 steps); wot elems 0-15 register-resident
//    across all tiles (values identical per step); ring ws[16] at
//    distance 16 streams elems 16-63.
//  - Per-XCD read set ~1.6 MB < 4 MB L2 (R7 churn check).
__global__ __launch_bounds__(512, 2) void outer_kernel(
    const __bf16* __restrict__ At2, const __bf16* __restrict__ Bt2,
    const float* __restrict__ rnorm, const __bf16* __restrict__ wot4,
    const float* __restrict__ bo, float* __restrict__ out)
{
  __shared__ __bf16 Ps[2][32 * 1032];   // 132096 B [buf][p][c*32+d]

  const int tid = threadIdx.x;
  const int w = tid >> 6, lane = tid & 63;
  const int half = lane >> 5, l31 = lane & 31;
  const int bxq = blockIdx.x;           // 0..3  -> j res [bxq*64, +64)
  const int by = blockIdx.y;            // 0..63 -> i res [by*4, +4)

  if (w < 4) {
    // ================= G1 producer waves =================
    const int mh = w >> 1;              // i-pair (0..1)
    const int nh = w & 1;               // j-quad (0..1), 4 j's each
    const __bf16* Ap = At2 + ((size_t)(by * 4 + mh * 2)) * 4096 + l31 * 8;

    auto g1tile = [&](int tt) {
      const int buf = tt & 1;
      const int jb = bxq * 64 + tt * 8;
      const __bf16* Bp = Bt2 + ((size_t)(jb + nh * 4)) * 4096 + l31 * 8;

      float rn[2][4];
      #pragma unroll
      for (int ti = 0; ti < 2; ++ti)
        #pragma unroll
        for (int tj = 0; tj < 4; ++tj)
          rn[ti][tj] = rnorm[(by * 4 + mh * 2 + ti) * NRES + jb + nh * 4 + tj];

      v16f acc[2][4];
      #pragma unroll
      for (int a = 0; a < 2; ++a)
        #pragma unroll
        for (int b = 0; b < 4; ++b)
          #pragma unroll
          for (int r = 0; r < 16; ++r) acc[a][b][r] = 0.f;

      #pragma unroll
      for (int ks = 0; ks < 8; ++ks) {
        const int off = (ks * 2 + half) * 256;
        v8bf a0 = *(const v8bf*)(Ap + off);
        v8bf a1 = *(const v8bf*)(Ap + 4096 + off);
        v8bf b0 = *(const v8bf*)(Bp + off);
        v8bf b1 = *(const v8bf*)(Bp + 4096 + off);
        v8bf b2 = *(const v8bf*)(Bp + 8192 + off);
        v8bf b3 = *(const v8bf*)(Bp + 12288 + off);
        acc[0][0] = MFMA32(a0, b0, acc[0][0]);
        acc[0][1] = MFMA32(a0, b1, acc[0][1]);
        acc[0][2] = MFMA32(a0, b2, acc[0][2]);
        acc[0][3] = MFMA32(a0, b3, acc[0][3]);
        acc[1][0] = MFMA32(a1, b0, acc[1][0]);
        acc[1][1] = MFMA32(a1, b1, acc[1][1]);
        acc[1][2] = MFMA32(a1, b2, acc[1][2]);
        acc[1][3] = MFMA32(a1, b3, acc[1][3]);
      }

      #pragma unroll
      for (int ti = 0; ti < 2; ++ti) {
        #pragma unroll
        for (int tj = 0; tj < 4; ++tj) {
          const int p = (mh * 2 + ti) * 8 + nh * 4 + tj;
          #pragma unroll
          for (int r = 0; r < 16; ++r) {
            int cc = (r & 3) + 8 * (r >> 2) + 4 * half;
            Ps[buf][p * 1032 + cc * 32 + l31] =
                (__bf16)(acc[ti][tj][r] * rn[ti][tj]);
          }
        }
      }
    };

    g1tile(0);
    __syncthreads();                    // Ps[0] ready
    #pragma unroll 1
    for (int t = 0; t < NT; ++t) {
      if (t < NT - 1) g1tile(t + 1);
      if (t < NT - 1) __syncthreads();  // Ps[(t+1)&1] ready / handoff
    }
  } else {
    // ================= G2 consumer waves =================
    const int zg = w - 4;               // z-quarter (0..3)
    const __bf16* wp = wot4 + (size_t)zg * 32768 + (half * 32 + l31) * 8;
    const float bz = bo[zg * 32 + l31];

    // wot elems 0..15 resident across all tiles (same values each step)
    v8bf wb[16];
    #pragma unroll
    for (int u = 0; u < 16; ++u) wb[u] = *(const v8bf*)(wp + u * 512);

    __syncthreads();                    // Ps[0] ready
    #pragma unroll 1
    for (int t = 0; t < NT; ++t) {
      const __bf16* pp = &Ps[t & 1][l31 * 1032 + half * 8];

      v16f c20, c21;
      #pragma unroll
      for (int r = 0; r < 16; ++r) { c20[r] = 0.f; c21[r] = 0.f; }

      v8bf ws[16];  // stream ring, distance 16, elems 16..63
      #pragma unroll
      for (int kk = 0; kk < 64; ++kk) {
        v8bf aa = *(const v8bf*)(pp + kk * 16);
        v8bf bb = (kk < 16) ? wb[kk] : ws[kk & 15];
        if (kk & 1) c21 = MFMA32(aa, bb, c21);
        else        c20 = MFMA32(aa, bb, c20);
        // ring load AFTER the read (read-then-write slot discipline):
        // value kk+16 into slot (kk+16)&15 == kk&15, consumed at kk+16.
        if (kk < 48)
          ws[kk & 15] = *(const v8bf*)(wp + (kk + 16) * 512);
      }

      // store tile t directly (full-K accumulators; no redb, no barrier)
      #pragma unroll
      for (int r = 0; r < 16; ++r) {
        int cc = (r & 3) + 8 * (r >> 2) + 4 * half;   // = p row
        int i = by * 4 + (cc >> 3);
        int j = bxq * 64 + t * 8 + (cc & 7);
        out[((size_t)i * NRES + j) * CZQ + zg * 32 + l31] =
            c20[r] + c21[r] + bz;
      }

      if (t < NT - 1) __syncthreads();  // matches G1's per-step barrier
    }
  }
}

extern "C" void kernel_launch(void* const* d_in, const int* in_sizes, int n_in,
                              void* d_out, int out_size, void* d_ws, size_t ws_size,
                              hipStream_t stream) {
  const float* msa  = (const float*)d_in[0];
  const float* mask = (const float*)d_in[1];
  const float* lnw  = (const float*)d_in[2];
  const float* lnb  = (const float*)d_in[3];
  const float* wl   = (const float*)d_in[4];
  const float* bl   = (const float*)d_in[5];
  const float* wr   = (const float*)d_in[6];
  const float* br   = (const float*)d_in[7];
  const float* wo   = (const float*)d_in[8];
  const float* bo   = (const float*)d_in[9];
  float* out = (float*)d_out;

  char* ws = (char*)d_ws;
  __bf16* At2   = (__bf16*)(ws);                    // 2 MB
  __bf16* Bt2   = (__bf16*)(ws + 2097152);          // 2 MB
  float*  rnorm = (float*)(ws + 4194304);           // 256 KB
  __bf16* wot4  = (__bf16*)(ws + 4456448);          // 256 KB

  fusedA_kernel<<<256, 512, 0, stream>>>(msa, lnw, lnb, wl, wr, mask, wo,
                                         bl, br, At2, Bt2, rnorm, wot4);
  outer_kernel<<<dim3(4, 64), 512, 0, stream>>>(At2, Bt2, rnorm, wot4, bo, out);
}